// Round 1
// baseline (295.581 us; speedup 1.0000x reference)
//
#include <hip/hip_runtime.h>
#include <hip/hip_bf16.h>

#define Nn 50000
#define DEG 16
#define IN_F 512
#define HID 128
#define OUT_F 64
#define SLOPE 0.2f

typedef __attribute__((ext_vector_type(8))) short bf16x8;
typedef __attribute__((ext_vector_type(4))) float f32x4;
typedef __attribute__((ext_vector_type(4))) unsigned int u32x4;

__device__ __forceinline__ unsigned short f2bf(float f) {
    return __builtin_bit_cast(unsigned short, __float2bfloat16(f));
}

// ---------- prep: transpose W1/W2 to [F][K] bf16, probe index width ----------
__global__ void __launch_bounds__(256) prep_kernel(
        const float* __restrict__ W1, const float* __restrict__ W2,
        const int* __restrict__ row_ptr,
        unsigned short* __restrict__ w1t, unsigned short* __restrict__ w2t,
        int* __restrict__ flag64) {
    int g = blockIdx.x * 256 + threadIdx.x;
    if (g == 0) {
        // int32 layout: row_ptr words = [0,16,32,...]; int64: [0,0,16,0,...]
        *flag64 = (row_ptr[1] == DEG) ? 0 : 1;
    }
    if (g < HID * IN_F) {                    // w1t[c*512 + k] = bf16(W1[k][c])
        int c = g >> 9, k = g & 511;
        w1t[g] = f2bf(W1[k * HID + c]);
    } else {
        int g2 = g - HID * IN_F;
        if (g2 < OUT_F * HID) {              // w2t[c*128 + k] = bf16(W2[k][c])
            int c = g2 >> 7, k = g2 & 127;
            w2t[g2] = f2bf(W2[k * OUT_F + c]);
        }
    }
}

// ---------- bf16 MFMA GEMM: C[M][F] = A[M][K] (fp32, cvt on the fly) @ WT^T ----------
// WT is [F][K] bf16 (row-major). Block = 256 threads = 4 waves.
// Wave tile: 32 rows x 64 cols (2 A-frags, 4 n-tiles). NWC col-wave-groups.
template<int K, int F, int NWC, int KC>
__global__ void __launch_bounds__(256) gemm_mfma(
        const float* __restrict__ A, const unsigned short* __restrict__ WT,
        float* __restrict__ C, int M) {
    constexpr int NWR = 4 / NWC;
    constexpr int BM  = NWR * 32;
    constexpr int STR = KC + 8;          // +8 bf16 pad: conflict-free b128 frag reads
    constexpr int NCH = K / KC;
    __shared__ unsigned short wt[F * STR];

    const int tid  = threadIdx.x;
    const int lane = tid & 63;
    const int w    = tid >> 6;
    const int wr   = w / NWC, wc = w % NWC;
    const int ln   = lane & 15, q = lane >> 4;

    const int mb = blockIdx.x * BM + wr * 32;
    int m0 = mb + ln;      if (m0 > M - 1) m0 = M - 1;
    int m1 = mb + 16 + ln; if (m1 > M - 1) m1 = M - 1;
    const float* a0p = A + (size_t)m0 * K;
    const float* a1p = A + (size_t)m1 * K;

    f32x4 acc[2][4] = {};

    for (int ch = 0; ch < NCH; ++ch) {
        const int k0 = ch * KC;
        // stage WT[:, k0:k0+KC] -> LDS (coalesced uint4 copies)
        constexpr int NCP = F * KC / 8 / 256;
        #pragma unroll
        for (int i = 0; i < NCP; ++i) {
            int idx = tid + i * 256;
            int c   = idx / (KC / 8);
            int k8  = (idx % (KC / 8)) * 8;
            *(u32x4*)&wt[c * STR + k8] = *(const u32x4*)&WT[(size_t)c * K + k0 + k8];
        }
        __syncthreads();
        #pragma unroll
        for (int ks = 0; ks < KC / 32; ++ks) {
            const int kk = k0 + ks * 32 + q * 8;   // A[m][k]: m=lane&15, k=q*8+j
            f32x4 va0 = *(const f32x4*)(a0p + kk);
            f32x4 va1 = *(const f32x4*)(a0p + kk + 4);
            f32x4 vb0 = *(const f32x4*)(a1p + kk);
            f32x4 vb1 = *(const f32x4*)(a1p + kk + 4);
            bf16x8 af0, af1;
            #pragma unroll
            for (int jj = 0; jj < 4; ++jj) {
                af0[jj]     = (short)f2bf(va0[jj]);
                af0[jj + 4] = (short)f2bf(va1[jj]);
                af1[jj]     = (short)f2bf(vb0[jj]);
                af1[jj + 4] = (short)f2bf(vb1[jj]);
            }
            #pragma unroll
            for (int nt = 0; nt < 4; ++nt) {
                bf16x8 bfr = *(const bf16x8*)&wt[(wc * 64 + nt * 16 + ln) * STR + ks * 32 + q * 8];
                acc[0][nt] = __builtin_amdgcn_mfma_f32_16x16x32_bf16(af0, bfr, acc[0][nt], 0, 0, 0);
                acc[1][nt] = __builtin_amdgcn_mfma_f32_16x16x32_bf16(af1, bfr, acc[1][nt], 0, 0, 0);
            }
        }
        __syncthreads();
    }
    // D layout: col = lane&15, row = (lane>>4)*4 + reg  [measured m89/m91]
    #pragma unroll
    for (int fr = 0; fr < 2; ++fr) {
        #pragma unroll
        for (int r = 0; r < 4; ++r) {
            int grow = mb + fr * 16 + q * 4 + r;
            if (grow < M) {
                #pragma unroll
                for (int nt = 0; nt < 4; ++nt)
                    C[(size_t)grow * F + wc * 64 + nt * 16 + ln] = acc[fr][nt][r];
            }
        }
    }
}

// ---------- el/er: per-row dot with attn vectors (one wave per row) ----------
template<int F>
__global__ void __launch_bounds__(256) elr_kernel(
        const float* __restrict__ h, const float* __restrict__ al,
        const float* __restrict__ ar, float* __restrict__ el, float* __restrict__ er) {
    int lane = threadIdx.x & 63;
    int row  = blockIdx.x * 4 + (threadIdx.x >> 6);
    const float* hr = h + (size_t)row * F;
    float sl = 0.f, sr = 0.f;
    #pragma unroll
    for (int i = 0; i < F / 64; ++i) {
        float v = hr[lane + i * 64];
        sl += v * al[lane + i * 64];
        sr += v * ar[lane + i * 64];
    }
    #pragma unroll
    for (int off = 32; off; off >>= 1) {
        sl += __shfl_xor(sl, off);
        sr += __shfl_xor(sr, off);
    }
    if (lane == 0) { el[row] = sl; er[row] = sr; }
}

// ---------- per-node softmax + weighted aggregation (one wave per node) ----------
template<int F>
__global__ void __launch_bounds__(256) agg_kernel(
        const int* __restrict__ col, const int* __restrict__ flag64,
        const float* __restrict__ el, const float* __restrict__ er,
        const float* __restrict__ h, const float* __restrict__ bias,
        float* __restrict__ out) {
    int lane = threadIdx.x & 63;
    int node = blockIdx.x * 4 + (threadIdx.x >> 6);
    int j    = lane & 15;
    long long e = (long long)node * DEG + j;
    int src;
    if (*flag64) src = (int)((const long long*)col)[e];
    else         src = col[e];
    float sc = el[node] + er[src];
    sc = sc >= 0.f ? sc : SLOPE * sc;
    float mx = sc;
    #pragma unroll
    for (int msk = 1; msk < 16; msk <<= 1) mx = fmaxf(mx, __shfl_xor(mx, msk, 16));
    float ex = __expf(sc - mx);
    float sm = ex;
    #pragma unroll
    for (int msk = 1; msk < 16; msk <<= 1) sm += __shfl_xor(sm, msk, 16);
    float alpha = ex / sm;

    float acc[F / 64] = {};
    #pragma unroll
    for (int jj = 0; jj < DEG; ++jj) {
        int   sj = __shfl(src, jj, 16);
        float aj = __shfl(alpha, jj, 16);
        const float* hs = h + (size_t)sj * F;
        #pragma unroll
        for (int i = 0; i < F / 64; ++i) acc[i] += aj * hs[lane + i * 64];
    }
    #pragma unroll
    for (int i = 0; i < F / 64; ++i)
        out[(size_t)node * F + lane + i * 64] = acc[i] + bias[lane + i * 64];
}

extern "C" void kernel_launch(void* const* d_in, const int* in_sizes, int n_in,
                              void* d_out, int out_size, void* d_ws, size_t ws_size,
                              hipStream_t stream) {
    const int*   row_ptr = (const int*)d_in[0];
    const int*   col_idx = (const int*)d_in[1];
    const float* x   = (const float*)d_in[2];
    const float* W1  = (const float*)d_in[3];
    const float* al1 = (const float*)d_in[4];
    const float* ar1 = (const float*)d_in[5];
    const float* b1  = (const float*)d_in[6];
    const float* W2  = (const float*)d_in[7];
    const float* al2 = (const float*)d_in[8];
    const float* ar2 = (const float*)d_in[9];
    const float* b2  = (const float*)d_in[10];
    float* out = (float*)d_out;

    float* ws   = (float*)d_ws;
    float* h1   = ws;                        // 50000*128 = 6.4M floats
    float* out1 = ws + 6400000;              // 6.4M
    float* h2   = ws + 12800000;             // 3.2M
    float* el1  = ws + 16000000;             // 50k each
    float* er1  = ws + 16050000;
    float* el2  = ws + 16100000;
    float* er2  = ws + 16150000;
    unsigned short* w1t = (unsigned short*)(ws + 16200000);   // 128*512 bf16
    unsigned short* w2t = (unsigned short*)(ws + 16232768);   // 64*128 bf16
    int* flag64 = (int*)(ws + 16236864);

    prep_kernel<<<(HID * IN_F + OUT_F * HID + 255) / 256, 256, 0, stream>>>(
        W1, W2, row_ptr, w1t, w2t, flag64);

    gemm_mfma<512, 128, 2, 128><<<(Nn + 63) / 64, 256, 0, stream>>>(x, w1t, h1, Nn);
    elr_kernel<128><<<Nn / 4, 256, 0, stream>>>(h1, al1, ar1, el1, er1);
    agg_kernel<128><<<Nn / 4, 256, 0, stream>>>(col_idx, flag64, el1, er1, h1, b1, out1);

    gemm_mfma<128, 64, 1, 128><<<(Nn + 127) / 128, 256, 0, stream>>>(out1, w2t, h2, Nn);
    elr_kernel<64><<<Nn / 4, 256, 0, stream>>>(h2, al2, ar2, el2, er2);
    agg_kernel<64><<<Nn / 4, 256, 0, stream>>>(col_idx, flag64, el2, er2, h2, b2, out);
}

// Round 2
// 270.585 us; speedup vs baseline: 1.0924x; 1.0924x over previous
//
#include <hip/hip_runtime.h>
#include <hip/hip_bf16.h>

#define Nn 50000
#define DEG 16
#define IN_F 512
#define HID 128
#define OUT_F 64
#define SLOPE 0.2f

typedef __attribute__((ext_vector_type(8))) short bf16x8;
typedef __attribute__((ext_vector_type(4))) short bf16x4;
typedef __attribute__((ext_vector_type(4))) float f32x4;
typedef __attribute__((ext_vector_type(4))) unsigned int u32x4;

__device__ __forceinline__ unsigned short f2bf(float f) {
    return __builtin_bit_cast(unsigned short, __float2bfloat16(f));
}
__device__ __forceinline__ float bf2f(unsigned short u) {
    return __bfloat162float(__builtin_bit_cast(__hip_bfloat16, u));
}

// ---------- prep: transpose W1/W2 to [F][K] bf16, probe index width ----------
__global__ void __launch_bounds__(256) prep_kernel(
        const float* __restrict__ W1, const float* __restrict__ W2,
        const int* __restrict__ row_ptr,
        unsigned short* __restrict__ w1t, unsigned short* __restrict__ w2t,
        int* __restrict__ flag64) {
    int g = blockIdx.x * 256 + threadIdx.x;
    if (g == 0) {
        // int32 layout: row_ptr words = [0,16,32,...]; int64: [0,0,16,0,...]
        *flag64 = (row_ptr[1] == DEG) ? 0 : 1;
    }
    if (g < HID * IN_F) {                    // w1t[c*512 + k] = bf16(W1[k][c])
        int c = g >> 9, k = g & 511;
        w1t[g] = f2bf(W1[k * HID + c]);
    } else {
        int g2 = g - HID * IN_F;
        if (g2 < OUT_F * HID) {              // w2t[c*128 + k] = bf16(W2[k][c])
            int c = g2 >> 7, k = g2 & 127;
            w2t[g2] = f2bf(W2[k * OUT_F + c]);
        }
    }
}

// ---------- MFMA GEMM + fused el/er epilogue, bf16 H output ----------
// A staged through LDS with coalesced loads (fp32->bf16 cvt for layer1,
// direct bf16 for layer2). WT is [F][K] bf16. 256 threads = 4 waves.
// Wave tile 32 rows x 64 cols; NWC column wave-groups, NWR=4/NWC row groups.
// LDS stride KC+8 bf16: ds_read_b128 frag reads are bank-conflict-free
// (bank group = 4*((row+q)%8), all 8 groups hit evenly).
template<int K, int F, int NWC, int KC, bool A_BF16>
__global__ void __launch_bounds__(256) gemm_fused(
        const void* __restrict__ Ain, const unsigned short* __restrict__ WT,
        const float* __restrict__ alv, const float* __restrict__ arv,
        unsigned short* __restrict__ Hb, float* __restrict__ el,
        float* __restrict__ er, int M) {
    constexpr int NWR = 4 / NWC;
    constexpr int BM  = NWR * 32;
    constexpr int STR = KC + 8;
    constexpr int NCH = K / KC;
    __shared__ unsigned short wt[F * STR];
    __shared__ unsigned short at[BM * STR];
    __shared__ float redl[BM][NWC];
    __shared__ float redr[BM][NWC];

    const int tid  = threadIdx.x;
    const int lane = tid & 63;
    const int w    = tid >> 6;
    const int wr   = w / NWC, wc = w % NWC;
    const int ln   = lane & 15, q = lane >> 4;
    const int mb   = blockIdx.x * BM;

    f32x4 acc[2][4] = {};

    for (int ch = 0; ch < NCH; ++ch) {
        const int k0 = ch * KC;
        // ---- stage B chunk (coalesced 16B per lane) ----
        constexpr int NCPB = F * KC / 8 / 256;
        #pragma unroll
        for (int i = 0; i < NCPB; ++i) {
            int idx = tid + i * 256;
            int c   = idx / (KC / 8);
            int k8  = (idx % (KC / 8)) * 8;
            *(u32x4*)&wt[c * STR + k8] = *(const u32x4*)&WT[(size_t)c * K + k0 + k8];
        }
        // ---- stage A tile (coalesced full-row segments) ----
        if (A_BF16) {
            const unsigned short* Ab = (const unsigned short*)Ain;
            constexpr int TPR = KC / 8;       // 16B per thread
            constexpr int RPS = 256 / TPR;
            #pragma unroll
            for (int s = 0; s < BM / RPS; ++s) {
                int row = s * RPS + tid / TPR;
                int k8  = (tid % TPR) * 8;
                int rg  = mb + row; if (rg > M - 1) rg = M - 1;
                *(u32x4*)&at[row * STR + k8] = *(const u32x4*)&Ab[(size_t)rg * K + k0 + k8];
            }
        } else {
            const float* Af = (const float*)Ain;
            constexpr int TPR = KC / 4;       // f32x4 per thread
            constexpr int RPS = 256 / TPR;
            #pragma unroll
            for (int s = 0; s < BM / RPS; ++s) {
                int row = s * RPS + tid / TPR;
                int c4  = (tid % TPR) * 4;
                int rg  = mb + row; if (rg > M - 1) rg = M - 1;
                f32x4 v = *(const f32x4*)&Af[(size_t)rg * K + k0 + c4];
                bf16x4 b;
                #pragma unroll
                for (int jj = 0; jj < 4; ++jj) b[jj] = (short)f2bf(v[jj]);
                *(bf16x4*)&at[row * STR + c4] = b;
            }
        }
        __syncthreads();
        #pragma unroll
        for (int ks = 0; ks < KC / 32; ++ks) {
            bf16x8 af0 = *(const bf16x8*)&at[(wr * 32 + ln) * STR + ks * 32 + q * 8];
            bf16x8 af1 = *(const bf16x8*)&at[(wr * 32 + 16 + ln) * STR + ks * 32 + q * 8];
            #pragma unroll
            for (int nt = 0; nt < 4; ++nt) {
                bf16x8 bfr = *(const bf16x8*)&wt[(wc * 64 + nt * 16 + ln) * STR + ks * 32 + q * 8];
                acc[0][nt] = __builtin_amdgcn_mfma_f32_16x16x32_bf16(af0, bfr, acc[0][nt], 0, 0, 0);
                acc[1][nt] = __builtin_amdgcn_mfma_f32_16x16x32_bf16(af1, bfr, acc[1][nt], 0, 0, 0);
            }
        }
        __syncthreads();
    }

    // ---- fused epilogue: bf16 H store + el/er row dots ----
    // D layout: col = lane&15 (ln), row = q*4 + reg  [measured m89/m91]
    float av[4], bv[4];
    #pragma unroll
    for (int nt = 0; nt < 4; ++nt) {
        av[nt] = alv[wc * 64 + nt * 16 + ln];
        bv[nt] = arv[wc * 64 + nt * 16 + ln];
    }
    #pragma unroll
    for (int fr = 0; fr < 2; ++fr) {
        #pragma unroll
        for (int r = 0; r < 4; ++r) {
            float sl = 0.f, sr = 0.f;
            #pragma unroll
            for (int nt = 0; nt < 4; ++nt) {
                float v = acc[fr][nt][r];
                sl += v * av[nt];
                sr += v * bv[nt];
            }
            #pragma unroll
            for (int m = 1; m < 16; m <<= 1) {
                sl += __shfl_xor(sl, m);
                sr += __shfl_xor(sr, m);
            }
            int rowl = wr * 32 + fr * 16 + q * 4 + r;
            if (ln == 0) { redl[rowl][wc] = sl; redr[rowl][wc] = sr; }
            int grow = mb + rowl;
            if (grow < M) {
                #pragma unroll
                for (int nt = 0; nt < 4; ++nt)
                    Hb[(size_t)grow * F + wc * 64 + nt * 16 + ln] = f2bf(acc[fr][nt][r]);
            }
        }
    }
    __syncthreads();
    if (tid < BM && mb + tid < M) {
        float s1 = redl[tid][0], s2 = redr[tid][0];
        if constexpr (NWC == 2) { s1 += redl[tid][1]; s2 += redr[tid][1]; }
        el[mb + tid] = s1;
        er[mb + tid] = s2;
    }
}

// ---------- agg layer1: bf16 h gather (256B rows), bf16 out (+bias) ----------
__global__ void __launch_bounds__(256) agg1_k(
        const int* __restrict__ col, const int* __restrict__ flag64,
        const float* __restrict__ el, const float* __restrict__ er,
        const unsigned short* __restrict__ Hb, const float* __restrict__ bias,
        unsigned short* __restrict__ Ob) {
    int lane = threadIdx.x & 63;
    int node = blockIdx.x * 4 + (threadIdx.x >> 6);
    int j    = lane & 15;
    int e    = node * DEG + j;
    int src  = (*flag64) ? (int)((const long long*)col)[e] : col[e];
    float sc = el[node] + er[src];
    sc = sc >= 0.f ? sc : SLOPE * sc;
    float mx = sc;
    #pragma unroll
    for (int m = 1; m < 16; m <<= 1) mx = fmaxf(mx, __shfl_xor(mx, m));
    float ex = __expf(sc - mx);
    float sm = ex;
    #pragma unroll
    for (int m = 1; m < 16; m <<= 1) sm += __shfl_xor(sm, m);
    float alpha = ex / sm;

    float a0 = 0.f, a1 = 0.f;
    #pragma unroll
    for (int jj = 0; jj < DEG; ++jj) {
        int   sj = __shfl(src, jj, 16);
        float aj = __shfl(alpha, jj, 16);
        unsigned int hv = *(const unsigned int*)&Hb[(size_t)sj * HID + lane * 2];
        a0 += aj * bf2f((unsigned short)(hv & 0xffffu));
        a1 += aj * bf2f((unsigned short)(hv >> 16));
    }
    a0 += bias[lane * 2];
    a1 += bias[lane * 2 + 1];
    unsigned int pk = (unsigned int)f2bf(a0) | ((unsigned int)f2bf(a1) << 16);
    *(unsigned int*)&Ob[(size_t)node * HID + lane * 2] = pk;
}

// ---------- agg layer2: bf16 h gather (128B rows), fp32 out (+bias) ----------
__global__ void __launch_bounds__(256) agg2_k(
        const int* __restrict__ col, const int* __restrict__ flag64,
        const float* __restrict__ el, const float* __restrict__ er,
        const unsigned short* __restrict__ Hb, const float* __restrict__ bias,
        float* __restrict__ out) {
    int lane = threadIdx.x & 63;
    int node = blockIdx.x * 4 + (threadIdx.x >> 6);
    int j    = lane & 15;
    int e    = node * DEG + j;
    int src  = (*flag64) ? (int)((const long long*)col)[e] : col[e];
    float sc = el[node] + er[src];
    sc = sc >= 0.f ? sc : SLOPE * sc;
    float mx = sc;
    #pragma unroll
    for (int m = 1; m < 16; m <<= 1) mx = fmaxf(mx, __shfl_xor(mx, m));
    float ex = __expf(sc - mx);
    float sm = ex;
    #pragma unroll
    for (int m = 1; m < 16; m <<= 1) sm += __shfl_xor(sm, m);
    float alpha = ex / sm;

    float a0 = 0.f;
    #pragma unroll
    for (int jj = 0; jj < DEG; ++jj) {
        int   sj = __shfl(src, jj, 16);
        float aj = __shfl(alpha, jj, 16);
        a0 += aj * bf2f(Hb[(size_t)sj * OUT_F + lane]);
    }
    out[(size_t)node * OUT_F + lane] = a0 + bias[lane];
}

extern "C" void kernel_launch(void* const* d_in, const int* in_sizes, int n_in,
                              void* d_out, int out_size, void* d_ws, size_t ws_size,
                              hipStream_t stream) {
    const int*   row_ptr = (const int*)d_in[0];
    const int*   col_idx = (const int*)d_in[1];
    const float* x   = (const float*)d_in[2];
    const float* W1  = (const float*)d_in[3];
    const float* al1 = (const float*)d_in[4];
    const float* ar1 = (const float*)d_in[5];
    const float* b1  = (const float*)d_in[6];
    const float* W2  = (const float*)d_in[7];
    const float* al2 = (const float*)d_in[8];
    const float* ar2 = (const float*)d_in[9];
    const float* b2  = (const float*)d_in[10];
    float* out = (float*)d_out;

    float* ws = (float*)d_ws;
    unsigned short* h1b = (unsigned short*)ws;                 // 6.4M bf16
    unsigned short* o1b = (unsigned short*)(ws + 3200000);     // 6.4M bf16
    unsigned short* h2b = (unsigned short*)(ws + 6400000);     // 3.2M bf16
    float* el1 = ws + 8000000;
    float* er1 = ws + 8050000;
    float* el2 = ws + 8100000;
    float* er2 = ws + 8150000;
    unsigned short* w1t = (unsigned short*)(ws + 8200000);     // 128*512 bf16
    unsigned short* w2t = (unsigned short*)(ws + 8232768);     // 64*128 bf16
    int* flag64 = (int*)(ws + 8236864);

    prep_kernel<<<(HID * IN_F + OUT_F * HID + 255) / 256, 256, 0, stream>>>(
        W1, W2, row_ptr, w1t, w2t, flag64);

    gemm_fused<512, 128, 2, 128, false><<<(Nn + 63) / 64, 256, 0, stream>>>(
        x, w1t, al1, ar1, h1b, el1, er1, Nn);
    agg1_k<<<Nn / 4, 256, 0, stream>>>(col_idx, flag64, el1, er1, h1b, b1, o1b);

    gemm_fused<128, 64, 1, 128, true><<<(Nn + 127) / 128, 256, 0, stream>>>(
        o1b, w2t, al2, ar2, h2b, el2, er2, Nn);
    agg2_k<<<Nn / 4, 256, 0, stream>>>(col_idx, flag64, el2, er2, h2b, b2, out);
}

// Round 3
// 256.462 us; speedup vs baseline: 1.1525x; 1.0551x over previous
//
#include <hip/hip_runtime.h>
#include <hip/hip_bf16.h>

#define Nn 50000
#define DEG 16
#define IN_F 512
#define HID 128
#define OUT_F 64
#define SLOPE 0.2f

typedef __attribute__((ext_vector_type(8))) short bf16x8;
typedef __attribute__((ext_vector_type(4))) float f32x4;

__device__ __forceinline__ unsigned short f2bf(float f) {
    return __builtin_bit_cast(unsigned short, __float2bfloat16(f));
}
__device__ __forceinline__ float bf2f(unsigned short u) {
    return __bfloat162float(__builtin_bit_cast(__hip_bfloat16, u));
}

// ---------- prep: W1/W2 -> [F][K] bf16. Coalesced READS, scattered writes ----------
__global__ void __launch_bounds__(256) prep_kernel(
        const float* __restrict__ W1, const float* __restrict__ W2,
        const int* __restrict__ row_ptr,
        unsigned short* __restrict__ w1t, unsigned short* __restrict__ w2t,
        int* __restrict__ flag64) {
    int g = blockIdx.x * 256 + threadIdx.x;
    if (g == 0) {
        // int32 layout: row_ptr words = [0,16,32,...]; int64: [0,0,16,0,...]
        *flag64 = (row_ptr[1] == DEG) ? 0 : 1;
    }
    if (g < IN_F * HID) {                     // read W1 linearly: k = g>>7, c = g&127
        int k = g >> 7, c = g & 127;
        w1t[c * IN_F + k] = f2bf(W1[g]);      // scattered 2B write (fire-and-forget)
    } else {
        int g2 = g - IN_F * HID;
        if (g2 < HID * OUT_F) {               // k = g2>>6, c = g2&63
            int k = g2 >> 6, c = g2 & 63;
            w2t[c * HID + k] = f2bf(W2[g2]);
        }
    }
}

// ---------- barrier-free register GEMM + fused el/er epilogue ----------
// C[M][F] = A[M][K] @ WT^T, WT = [F][K] bf16 (L2-resident, loaded as frags
// directly from global). Each wave owns 32 rows x F cols; no LDS, no syncs —
// the K-loop is a pure chain of independent loads + MFMAs the compiler can
// software-pipeline. A fp32 rows are read as full 128B spans per ks (cvt to
// bf16 in-register); A bf16 rows as 64B spans.
template<int K, int F, bool A_BF16>
__global__ void __launch_bounds__(256) gemm_reg(
        const void* __restrict__ Ain, const unsigned short* __restrict__ WT,
        const float* __restrict__ alv, const float* __restrict__ arv,
        unsigned short* __restrict__ Hb, float* __restrict__ el,
        float* __restrict__ er, int M) {
    constexpr int NT = F / 16;
    const int tid  = threadIdx.x;
    const int lane = tid & 63;
    const int w    = tid >> 6;
    const int ln   = lane & 15, q = lane >> 4;
    const int mb   = blockIdx.x * 128 + w * 32;

    int m0 = mb + ln;      if (m0 > M - 1) m0 = M - 1;
    int m1 = mb + 16 + ln; if (m1 > M - 1) m1 = M - 1;

    f32x4 acc[2][NT] = {};
    const unsigned short* bb = WT + (size_t)ln * K;

    #pragma unroll
    for (int ks = 0; ks < K / 32; ++ks) {
        const int kk = ks * 32 + q * 8;       // A[m][k]: m=lane&15, k=q*8+j
        bf16x8 af0, af1;
        if constexpr (A_BF16) {
            const unsigned short* Ab = (const unsigned short*)Ain;
            af0 = *(const bf16x8*)&Ab[(size_t)m0 * K + kk];
            af1 = *(const bf16x8*)&Ab[(size_t)m1 * K + kk];
        } else {
            const float* Af = (const float*)Ain;
            f32x4 va0 = *(const f32x4*)&Af[(size_t)m0 * K + kk];
            f32x4 va1 = *(const f32x4*)&Af[(size_t)m0 * K + kk + 4];
            f32x4 vb0 = *(const f32x4*)&Af[(size_t)m1 * K + kk];
            f32x4 vb1 = *(const f32x4*)&Af[(size_t)m1 * K + kk + 4];
            #pragma unroll
            for (int jj = 0; jj < 4; ++jj) {
                af0[jj]     = (short)f2bf(va0[jj]);
                af0[jj + 4] = (short)f2bf(va1[jj]);
                af1[jj]     = (short)f2bf(vb0[jj]);
                af1[jj + 4] = (short)f2bf(vb1[jj]);
            }
        }
        #pragma unroll
        for (int nt = 0; nt < NT; ++nt) {
            bf16x8 bfr = *(const bf16x8*)&bb[(size_t)nt * 16 * K + kk];
            acc[0][nt] = __builtin_amdgcn_mfma_f32_16x16x32_bf16(af0, bfr, acc[0][nt], 0, 0, 0);
            acc[1][nt] = __builtin_amdgcn_mfma_f32_16x16x32_bf16(af1, bfr, acc[1][nt], 0, 0, 0);
        }
    }

    // ---- fused epilogue: bf16 H store + el/er row dots (pure in-wave) ----
    // D layout: col = ln, row = q*4 + reg  [measured m89/m91]
    float av[NT], bv[NT];
    #pragma unroll
    for (int nt = 0; nt < NT; ++nt) {
        av[nt] = alv[nt * 16 + ln];
        bv[nt] = arv[nt * 16 + ln];
    }
    #pragma unroll
    for (int fr = 0; fr < 2; ++fr) {
        #pragma unroll
        for (int r = 0; r < 4; ++r) {
            float sl = 0.f, sr = 0.f;
            #pragma unroll
            for (int nt = 0; nt < NT; ++nt) {
                float v = acc[fr][nt][r];
                sl += v * av[nt];
                sr += v * bv[nt];
            }
            #pragma unroll
            for (int m = 1; m < 16; m <<= 1) {   // reduce across the 16-lane group
                sl += __shfl_xor(sl, m);
                sr += __shfl_xor(sr, m);
            }
            int grow = mb + fr * 16 + q * 4 + r;
            if (grow < M) {
                #pragma unroll
                for (int nt = 0; nt < NT; ++nt)
                    Hb[(size_t)grow * F + nt * 16 + ln] = f2bf(acc[fr][nt][r]);
                if (ln == 0) { el[grow] = sl; er[grow] = sr; }
            }
        }
    }
}

// ---------- agg layer1: bf16 h gather (256B rows), bf16 out (+bias) ----------
__global__ void __launch_bounds__(256) agg1_k(
        const int* __restrict__ col, const int* __restrict__ flag64,
        const float* __restrict__ el, const float* __restrict__ er,
        const unsigned short* __restrict__ Hb, const float* __restrict__ bias,
        unsigned short* __restrict__ Ob) {
    int lane = threadIdx.x & 63;
    int node = blockIdx.x * 4 + (threadIdx.x >> 6);
    int j    = lane & 15;
    int e    = node * DEG + j;
    int src  = (*flag64) ? (int)((const long long*)col)[e] : col[e];
    float sc = el[node] + er[src];
    sc = sc >= 0.f ? sc : SLOPE * sc;
    float mx = sc;
    #pragma unroll
    for (int m = 1; m < 16; m <<= 1) mx = fmaxf(mx, __shfl_xor(mx, m));
    float ex = __expf(sc - mx);
    float sm = ex;
    #pragma unroll
    for (int m = 1; m < 16; m <<= 1) sm += __shfl_xor(sm, m);
    float alpha = ex / sm;

    float a0 = 0.f, a1 = 0.f;
    #pragma unroll
    for (int jj = 0; jj < DEG; ++jj) {
        int   sj = __shfl(src, jj, 16);
        float aj = __shfl(alpha, jj, 16);
        unsigned int hv = *(const unsigned int*)&Hb[(size_t)sj * HID + lane * 2];
        a0 += aj * bf2f((unsigned short)(hv & 0xffffu));
        a1 += aj * bf2f((unsigned short)(hv >> 16));
    }
    a0 += bias[lane * 2];
    a1 += bias[lane * 2 + 1];
    unsigned int pk = (unsigned int)f2bf(a0) | ((unsigned int)f2bf(a1) << 16);
    *(unsigned int*)&Ob[(size_t)node * HID + lane * 2] = pk;
}

// ---------- agg layer2: bf16 h gather (128B rows), fp32 out (+bias) ----------
__global__ void __launch_bounds__(256) agg2_k(
        const int* __restrict__ col, const int* __restrict__ flag64,
        const float* __restrict__ el, const float* __restrict__ er,
        const unsigned short* __restrict__ Hb, const float* __restrict__ bias,
        float* __restrict__ out) {
    int lane = threadIdx.x & 63;
    int node = blockIdx.x * 4 + (threadIdx.x >> 6);
    int j    = lane & 15;
    int e    = node * DEG + j;
    int src  = (*flag64) ? (int)((const long long*)col)[e] : col[e];
    float sc = el[node] + er[src];
    sc = sc >= 0.f ? sc : SLOPE * sc;
    float mx = sc;
    #pragma unroll
    for (int m = 1; m < 16; m <<= 1) mx = fmaxf(mx, __shfl_xor(mx, m));
    float ex = __expf(sc - mx);
    float sm = ex;
    #pragma unroll
    for (int m = 1; m < 16; m <<= 1) sm += __shfl_xor(sm, m);
    float alpha = ex / sm;

    float a0 = 0.f;
    #pragma unroll
    for (int jj = 0; jj < DEG; ++jj) {
        int   sj = __shfl(src, jj, 16);
        float aj = __shfl(alpha, jj, 16);
        a0 += aj * bf2f(Hb[(size_t)sj * OUT_F + lane]);
    }
    out[(size_t)node * OUT_F + lane] = a0 + bias[lane];
}

extern "C" void kernel_launch(void* const* d_in, const int* in_sizes, int n_in,
                              void* d_out, int out_size, void* d_ws, size_t ws_size,
                              hipStream_t stream) {
    const int*   row_ptr = (const int*)d_in[0];
    const int*   col_idx = (const int*)d_in[1];
    const float* x   = (const float*)d_in[2];
    const float* W1  = (const float*)d_in[3];
    const float* al1 = (const float*)d_in[4];
    const float* ar1 = (const float*)d_in[5];
    const float* b1  = (const float*)d_in[6];
    const float* W2  = (const float*)d_in[7];
    const float* al2 = (const float*)d_in[8];
    const float* ar2 = (const float*)d_in[9];
    const float* b2  = (const float*)d_in[10];
    float* out = (float*)d_out;

    float* ws = (float*)d_ws;
    unsigned short* h1b = (unsigned short*)ws;                 // 6.4M bf16
    unsigned short* o1b = (unsigned short*)(ws + 3200000);     // 6.4M bf16
    unsigned short* h2b = (unsigned short*)(ws + 6400000);     // 3.2M bf16
    float* el1 = ws + 8000000;
    float* er1 = ws + 8050000;
    float* el2 = ws + 8100000;
    float* er2 = ws + 8150000;
    unsigned short* w1t = (unsigned short*)(ws + 8200000);     // 128*512 bf16
    unsigned short* w2t = (unsigned short*)(ws + 8232768);     // 64*128 bf16
    int* flag64 = (int*)(ws + 8236864);

    prep_kernel<<<(IN_F * HID + HID * OUT_F + 255) / 256, 256, 0, stream>>>(
        W1, W2, row_ptr, w1t, w2t, flag64);

    gemm_reg<512, 128, false><<<(Nn + 127) / 128, 256, 0, stream>>>(
        x, w1t, al1, ar1, h1b, el1, er1, Nn);
    agg1_k<<<Nn / 4, 256, 0, stream>>>(col_idx, flag64, el1, er1, h1b, b1, o1b);

    gemm_reg<128, 64, true><<<(Nn + 127) / 128, 256, 0, stream>>>(
        o1b, w2t, al2, ar2, h2b, el2, er2, Nn);
    agg2_k<<<Nn / 4, 256, 0, stream>>>(col_idx, flag64, el2, er2, h2b, b2, out);
}